// Round 1
// baseline (640.097 us; speedup 1.0000x reference)
//
#include <hip/hip_runtime.h>
#include <cstdint>
#include <cstddef>

typedef unsigned short ushort_t;
typedef __attribute__((ext_vector_type(8))) short short8;    // 8 bf16 (4 VGPRs)
typedef __attribute__((ext_vector_type(4))) float floatx4;

#define B_   32
#define T_   2048
#define H_   1024
#define U_   1024
#define KN_  32
#define KEXT 1056            // H + KN, = 33 * 32
#define BT_  (B_ * T_)       // 65536

// ---------- helpers ----------
__device__ __forceinline__ unsigned int f2bf_u(float f) {
    union { float f; unsigned int u; } v; v.f = f;
    unsigned int u = v.u;
    return (u + 0x7FFFu + ((u >> 16) & 1u)) >> 16;  // RNE
}
__device__ __forceinline__ float bflo(unsigned int u) {
    union { unsigned int u; float f; } v; v.u = u << 16; return v.f;
}
__device__ __forceinline__ float bfhi(unsigned int u) {
    union { unsigned int u; float f; } v; v.u = u & 0xffff0000u; return v.f;
}
__device__ __forceinline__ void async_cp16(const void* g, void* l) {
    __builtin_amdgcn_global_load_lds(
        (const __attribute__((address_space(1))) unsigned int*)g,
        (__attribute__((address_space(3))) unsigned int*)l, 16, 0, 0);
}
__device__ __forceinline__ float fast_tanh(float x) {
    float e = __expf(2.0f * x);
    return 1.0f - 2.0f * __builtin_amdgcn_rcpf(e + 1.0f);
}

#define WAITV(n) asm volatile("s_waitcnt vmcnt(" #n ")" ::: "memory")
#define BARX() do { asm volatile("" ::: "memory"); __builtin_amdgcn_s_barrier(); asm volatile("" ::: "memory"); } while (0)

// ---------- prep kernels (unchanged, measured-best forms) ----------
// values (B,T,H) f32 -> A[row][0:1024] bf16; 8 rows per block
__global__ void pack_values(const float* __restrict__ values, ushort_t* __restrict__ A) {
    const int tid = threadIdx.x;
    const size_t base = (size_t)blockIdx.x * 8;
#pragma unroll
    for (int r = 0; r < 8; ++r) {
        const size_t row = base + r;
        float4 v = reinterpret_cast<const float4*>(values + row * H_)[tid];
        ushort4 o;
        o.x = (ushort_t)f2bf_u(v.x); o.y = (ushort_t)f2bf_u(v.y);
        o.z = (ushort_t)f2bf_u(v.z); o.w = (ushort_t)f2bf_u(v.w);
        *reinterpret_cast<ushort4*>(A + row * KEXT + tid * 4) = o;
    }
}

// conv(prev_att, conv_w) -> A[row][1024:1056] bf16 (loc transposed to (b,t,k))
__global__ void conv_pack(const float* __restrict__ prev, const float* __restrict__ convw,
                          ushort_t* __restrict__ A) {
    __shared__ float satt[158];       // 128 + 2*15
    __shared__ float sw[KN_ * 31];
    const int tid = threadIdx.x;
    const int b = blockIdx.y, t0 = blockIdx.x * 128;
    for (int i = tid; i < 158; i += 256) {
        int t = t0 - 15 + i;
        satt[i] = (t >= 0 && t < T_) ? prev[b * T_ + t] : 0.0f;
    }
    for (int i = tid; i < KN_ * 31; i += 256) sw[i] = convw[i];
    __syncthreads();
    for (int idx = tid; idx < 128 * KN_; idx += 256) {
        const int k = idx & 31, tl = idx >> 5;
        float acc = 0.0f;
#pragma unroll
        for (int j = 0; j < 31; ++j) acc += satt[tl + j] * sw[k * 31 + j];
        A[(size_t)(b * T_ + t0 + tl) * KEXT + H_ + k] = (ushort_t)f2bf_u(acc);
    }
}

// per u: pack [W1_w | loc_proj] row to Bm bf16 AND bias[b][u] for all 32 b
__global__ void pack_w_bias(const float* __restrict__ W1w, const float* __restrict__ locp,
                            const float* __restrict__ W2w, const float* __restrict__ q,
                            const float* __restrict__ W1b, const float* __restrict__ W2b,
                            ushort_t* __restrict__ Bm, float* __restrict__ bias) {
    const int u = blockIdx.x, tid = threadIdx.x;
    {
        float4 v = reinterpret_cast<const float4*>(W1w + (size_t)u * H_)[tid];
        ushort4 o;
        o.x = (ushort_t)f2bf_u(v.x); o.y = (ushort_t)f2bf_u(v.y);
        o.z = (ushort_t)f2bf_u(v.z); o.w = (ushort_t)f2bf_u(v.w);
        *reinterpret_cast<ushort4*>(Bm + (size_t)u * KEXT + tid * 4) = o;
    }
    if (tid < 8) {
        float4 w = reinterpret_cast<const float4*>(locp + u * KN_)[tid];
        ushort4 o2;
        o2.x = (ushort_t)f2bf_u(w.x); o2.y = (ushort_t)f2bf_u(w.y);
        o2.z = (ushort_t)f2bf_u(w.z); o2.w = (ushort_t)f2bf_u(w.w);
        *reinterpret_cast<ushort4*>(Bm + (size_t)u * KEXT + H_ + tid * 4) = o2;
    }
    const int lane = tid & 63, wave = tid >> 6;
    const float* wr = W2w + (size_t)u * H_;
    float wv[16];
#pragma unroll
    for (int i = 0; i < 16; ++i) wv[i] = wr[lane + i * 64];
    const float bb = W1b[u] + W2b[u];
#pragma unroll
    for (int j = 0; j < 8; ++j) {
        const int b = wave * 8 + j;
        const float* qr = q + b * H_;
        float acc = 0.0f;
#pragma unroll
        for (int i = 0; i < 16; ++i) acc += wv[i] * qr[lane + i * 64];
#pragma unroll
        for (int off = 32; off >= 1; off >>= 1) acc += __shfl_xor(acc, off, 64);
        if (lane == 0) bias[b * U_ + u] = acc + bb;
    }
}

// ---------- fused score GEMM: 256x256 tile, BK=32, 8 waves, 3-deep LDS pipeline ----------
// Phase-split schedule (T3+T4+T5): per 32-K tile, two phases of
// {ds_read subtile || issue global_load_lds prefetch -> counted vmcnt -> barrier
//  -> setprio(1) -> 16 MFMA -> setprio(0) -> barrier}.
// vmcnt is counted (6/5 steady state), never 0 in the main loop; 3 LDS buffers
// give a 2-tile (4-phase) prefetch distance to cover HBM latency.
// XOR chunk swizzle: linear global_load_lds dest + pre-swizzled global source,
// same swizzle on ds_read (both-sides-or-neither). 8 words/bank uniform.
__global__ __launch_bounds__(512, 2)
void score_gemm(const ushort_t* __restrict__ A, const ushort_t* __restrict__ Bm,
                const float* __restrict__ bias, const float* __restrict__ Vw,
                float* __restrict__ sacc) {
    __shared__ __align__(16) ushort_t sm[3][2][8192];   // 3 bufs x (A,B) x 256x32 bf16 = 96 KiB
    const int tid  = threadIdx.x;
    const int wave = tid >> 6;
    const int lane = tid & 63;
    const int lr   = lane & 15;
    const int quad = lane >> 4;
    const int wr64 = (wave >> 2) * 64;   // wave m-offset (interleaved halves)
    const int wc32 = (wave & 3) * 32;    // wave n-offset (interleaved halves)

    // XCD-aware swizzle: each XCD owns a contiguous band of m-tiles; n fastest
    const int hid = blockIdx.x;                     // 0..1023
    const int lin = (hid & 7) * 128 + (hid >> 3);   // bijective (1024 % 8 == 0)
    const int m0 = (lin >> 2) * 256;                // 256 m-tiles
    const int n0 = (lin & 3) * 256;                 // 4 n-tiles

    const ushort_t* Ablk = A + (size_t)m0 * KEXT;
    const ushort_t* Bblk = Bm + (size_t)n0 * KEXT;

    // staging source offsets: chunk s = j*512+tid -> row = s>>2, phys = s&3,
    // logical chunk c = phys ^ (row&3)  (inverse-swizzled global source)
    int off[2];
#pragma unroll
    for (int j = 0; j < 2; ++j) {
        const int s = j * 512 + tid;
        const int row = s >> 2;
        const int c = (s & 3) ^ (row & 3);
        off[j] = row * KEXT + c * 8;
    }

    floatx4 acc[8][4] = {};
    short8 aF[8], bF[4];

    // prologue: stage tiles 0 (buf0) and 1 (buf1); order per tile: A0,A1,B0,B1
#pragma unroll
    for (int u = 0; u < 2; ++u) {
        async_cp16(Ablk + u * 32 + off[0], &sm[u][0][wave * 512]);
        async_cp16(Ablk + u * 32 + off[1], &sm[u][0][4096 + wave * 512]);
        async_cp16(Bblk + u * 32 + off[0], &sm[u][1][wave * 512]);
        async_cp16(Bblk + u * 32 + off[1], &sm[u][1][4096 + wave * 512]);
    }
    WAITV(5);   // oldest 3 = tile0 {A0,A1,B0} landed; tile0.B1 + tile1 in flight
    BARX();

    int cur = 0, nb = 2;
#pragma unroll 1
    for (int t = 0; t < 33; ++t) {
        const ushort_t* sA = &sm[cur][0][0];
        const ushort_t* sB = &sm[cur][1][0];

        // ---- phase A (n-half 0): read all A frags (reused in phase B) + B frags 0,1
#pragma unroll
        for (int mi = 0; mi < 8; ++mi) {
            const int row = (mi >> 2) * 128 + wr64 + (mi & 3) * 16 + lr;
            aF[mi] = *reinterpret_cast<const short8*>(sA + row * 32 + (quad ^ (row & 3)) * 8);
        }
        {
            const int r0 = wc32 + lr;
            bF[0] = *reinterpret_cast<const short8*>(sB + r0 * 32 + (quad ^ (r0 & 3)) * 8);
            const int r1 = wc32 + 16 + lr;
            bF[1] = *reinterpret_cast<const short8*>(sB + r1 * 32 + (quad ^ (r1 & 3)) * 8);
        }
        if (t <= 30) {   // stage (t+2).A into buf nb
            const ushort_t* gA = Ablk + (t + 2) * 32;
            async_cp16(gA + off[0], &sm[nb][0][wave * 512]);
            async_cp16(gA + off[1], &sm[nb][0][4096 + wave * 512]);
        }
        // guard (t).B1 for phase B: newer ops = (t+1).A,B + (t+2).A = 6 (edges: 4 / 0)
        if (t < 31)      { WAITV(6); }
        else if (t == 31){ WAITV(4); }
        else             { WAITV(0); }
        BARX();
        __builtin_amdgcn_s_setprio(1);
#pragma unroll
        for (int mi = 0; mi < 8; ++mi) {
            acc[mi][0] = __builtin_amdgcn_mfma_f32_16x16x32_bf16(aF[mi], bF[0], acc[mi][0], 0, 0, 0);
            acc[mi][1] = __builtin_amdgcn_mfma_f32_16x16x32_bf16(aF[mi], bF[1], acc[mi][1], 0, 0, 0);
        }
        __builtin_amdgcn_s_setprio(0);
        BARX();

        // ---- phase B (n-half 1): reuse aF, read B frags 2,3
        {
            const int r2 = 128 + wc32 + lr;
            bF[2] = *reinterpret_cast<const short8*>(sB + r2 * 32 + (quad ^ (r2 & 3)) * 8);
            const int r3 = 128 + wc32 + 16 + lr;
            bF[3] = *reinterpret_cast<const short8*>(sB + r3 * 32 + (quad ^ (r3 & 3)) * 8);
        }
        if (t <= 30) {   // stage (t+2).B into buf nb
            const ushort_t* gB = Bblk + (t + 2) * 32;
            async_cp16(gB + off[0], &sm[nb][1][wave * 512]);
            async_cp16(gB + off[1], &sm[nb][1][4096 + wave * 512]);
        }
        // guard (t+1).{A0,A1,B0} for next phase A: newer = (t+1).B1 + (t+2).A,B = 5 (edge: 1)
        if (t < 31)      { WAITV(5); }
        else if (t == 31){ WAITV(1); }
        BARX();
        __builtin_amdgcn_s_setprio(1);
#pragma unroll
        for (int mi = 0; mi < 8; ++mi) {
            acc[mi][2] = __builtin_amdgcn_mfma_f32_16x16x32_bf16(aF[mi], bF[2], acc[mi][2], 0, 0, 0);
            acc[mi][3] = __builtin_amdgcn_mfma_f32_16x16x32_bf16(aF[mi], bF[3], acc[mi][3], 0, 0, 0);
        }
        __builtin_amdgcn_s_setprio(0);
        BARX();

        cur = (cur == 2) ? 0 : cur + 1;
        nb  = (nb == 2) ? 0 : nb + 1;
    }

    // epilogue: sum_1 -> tanh -> *Vw -> reduce over this wave's 64 u-cols -> atomic partial
    const int bb = m0 >> 11;
    float vw[4], bv[4];
#pragma unroll
    for (int ni = 0; ni < 4; ++ni) {
        const int u = n0 + (ni >> 1) * 128 + wc32 + (ni & 1) * 16 + lr;
        vw[ni] = Vw[u];
        bv[ni] = bias[bb * U_ + u];
    }
#pragma unroll
    for (int mi = 0; mi < 8; ++mi) {
        const int mrow = m0 + (mi >> 2) * 128 + wr64 + (mi & 3) * 16 + quad * 4;
#pragma unroll
        for (int r = 0; r < 4; ++r) {
            float s = 0.0f;
#pragma unroll
            for (int ni = 0; ni < 4; ++ni)
                s += vw[ni] * fast_tanh(acc[mi][ni][r] + bv[ni]);
            s += __shfl_xor(s, 1, 64);
            s += __shfl_xor(s, 2, 64);
            s += __shfl_xor(s, 4, 64);
            s += __shfl_xor(s, 8, 64);
            if (lr == 0)
                atomicAdd(&sacc[mrow + r], s);
        }
    }
}

// ---------- softmax over T per b; writes score and attn outputs ----------
__global__ void softmax_k(const float* __restrict__ sacc, const float* __restrict__ Vb,
                          float* __restrict__ out) {
    const int b = blockIdx.x, tid = threadIdx.x;
    const int lane = tid & 63, wave = tid >> 6;
    const float vb = Vb[0];
    float v[8], e[8];
    float mx = -1e30f;
#pragma unroll
    for (int j = 0; j < 8; ++j) {
        v[j] = sacc[b * T_ + j * 256 + tid] + vb;
        out[98304 + b * T_ + j * 256 + tid] = v[j];   // score output
        mx = fmaxf(mx, v[j]);
    }
#pragma unroll
    for (int off = 32; off >= 1; off >>= 1) mx = fmaxf(mx, __shfl_xor(mx, off, 64));
    __shared__ float sm[4], ss[4];
    if (lane == 0) sm[wave] = mx;
    __syncthreads();
    mx = fmaxf(fmaxf(sm[0], sm[1]), fmaxf(sm[2], sm[3]));
    float sum = 0.0f;
#pragma unroll
    for (int j = 0; j < 8; ++j) { e[j] = __expf(v[j] - mx); sum += e[j]; }
#pragma unroll
    for (int off = 32; off >= 1; off >>= 1) sum += __shfl_xor(sum, off, 64);
    if (lane == 0) ss[wave] = sum;
    __syncthreads();
    sum = ss[0] + ss[1] + ss[2] + ss[3];
    const float inv = 1.0f / sum;
#pragma unroll
    for (int j = 0; j < 8; ++j)
        out[32768 + b * T_ + j * 256 + tid] = e[j] * inv;  // attention output
}

// ---------- context = sum_t attn[b,t] * values[b,t,h] (bf16 copy) ----------
__global__ void context_k(const ushort_t* __restrict__ A, const float* __restrict__ attn,
                          float* __restrict__ ctx) {
    const int b = blockIdx.y, tc = blockIdx.x, tid = threadIdx.x;
    __shared__ float sa[128];
    if (tid < 128) sa[tid] = attn[b * T_ + tc * 128 + tid];
    __syncthreads();
    const int hh = (tid & 127) * 8;   // 8 h-elements per thread
    const int tp = tid >> 7;          // row-pair 0/1
    const ushort_t* base = A + (size_t)(b * T_ + tc * 128 + tp) * KEXT + hh;
    float a[8] = {0, 0, 0, 0, 0, 0, 0, 0};
    for (int t = 0; t < 128; t += 2) {
        const float w = sa[t + tp];
        uint4 u = *reinterpret_cast<const uint4*>(base + (size_t)t * KEXT);
        a[0] += w * bflo(u.x); a[1] += w * bfhi(u.x);
        a[2] += w * bflo(u.y); a[3] += w * bfhi(u.y);
        a[4] += w * bflo(u.z); a[5] += w * bfhi(u.z);
        a[6] += w * bflo(u.w); a[7] += w * bfhi(u.w);
    }
#pragma unroll
    for (int j = 0; j < 8; ++j)
        atomicAdd(&ctx[b * H_ + hh + j], a[j]);
}

// ---------- launch ----------
extern "C" void kernel_launch(void* const* d_in, const int* in_sizes, int n_in,
                              void* d_out, int out_size, void* d_ws, size_t ws_size,
                              hipStream_t stream) {
    const float* query    = (const float*)d_in[0];
    const float* values   = (const float*)d_in[1];
    const float* prev_att = (const float*)d_in[2];
    const float* W1w      = (const float*)d_in[3];
    const float* W1b      = (const float*)d_in[4];
    const float* W2w      = (const float*)d_in[5];
    const float* W2b      = (const float*)d_in[6];
    const float* Vw       = (const float*)d_in[7];
    const float* Vb       = (const float*)d_in[8];
    const float* convw    = (const float*)d_in[9];
    const float* locp     = (const float*)d_in[10];
    float* out = (float*)d_out;

    char* ws = (char*)d_ws;
    ushort_t* A    = (ushort_t*)(ws);
    ushort_t* Bm   = (ushort_t*)(ws + 138412032);
    float*    bias = (float*)(ws + 140574720);
    float*    sacc = (float*)(ws + 140705792);

    hipMemsetAsync(sacc, 0, BT_ * sizeof(float), stream);
    hipMemsetAsync(out, 0, 32768 * sizeof(float), stream);   // context via atomics

    pack_values<<<BT_ / 8, 256, 0, stream>>>(values, A);
    conv_pack<<<dim3(16, 32), 256, 0, stream>>>(prev_att, convw, A);
    pack_w_bias<<<1024, 256, 0, stream>>>(W1w, locp, W2w, query, W1b, W2b, Bm, bias);
    score_gemm<<<1024, 512, 0, stream>>>(A, Bm, bias, Vw, sacc);
    softmax_k<<<32, 256, 0, stream>>>(sacc, Vb, out);
    context_k<<<dim3(16, 32), 256, 0, stream>>>(A, out + 32768, out);
}

// Round 2
// 634.240 us; speedup vs baseline: 1.0092x; 1.0092x over previous
//
#include <hip/hip_runtime.h>
#include <cstdint>
#include <cstddef>

typedef unsigned short ushort_t;
typedef __attribute__((ext_vector_type(8))) short short8;    // 8 bf16 (4 VGPRs)
typedef __attribute__((ext_vector_type(4))) float floatx4;

#define B_   32
#define T_   2048
#define H_   1024
#define U_   1024
#define KN_  32
#define KEXT 1056            // H + KN, = 33 * 32
#define BT_  (B_ * T_)       // 65536

// ---------- helpers ----------
__device__ __forceinline__ unsigned int f2bf_u(float f) {
    union { float f; unsigned int u; } v; v.f = f;
    unsigned int u = v.u;
    return (u + 0x7FFFu + ((u >> 16) & 1u)) >> 16;  // RNE
}
__device__ __forceinline__ float bflo(unsigned int u) {
    union { unsigned int u; float f; } v; v.u = u << 16; return v.f;
}
__device__ __forceinline__ float bfhi(unsigned int u) {
    union { unsigned int u; float f; } v; v.u = u & 0xffff0000u; return v.f;
}
__device__ __forceinline__ void async_cp16(const void* g, void* l) {
    __builtin_amdgcn_global_load_lds(
        (const __attribute__((address_space(1))) unsigned int*)g,
        (__attribute__((address_space(3))) unsigned int*)l, 16, 0, 0);
}
__device__ __forceinline__ float fast_tanh(float x) {
    float e = __expf(2.0f * x);
    return 1.0f - 2.0f * __builtin_amdgcn_rcpf(e + 1.0f);
}

#define WAITV(n) asm volatile("s_waitcnt vmcnt(" #n ")" ::: "memory")
#define BARX() do { asm volatile("" ::: "memory"); __builtin_amdgcn_s_barrier(); asm volatile("" ::: "memory"); } while (0)

// ---------- prep kernels (unchanged, measured-best forms) ----------
// values (B,T,H) f32 -> A[row][0:1024] bf16; 8 rows per block
__global__ void pack_values(const float* __restrict__ values, ushort_t* __restrict__ A) {
    const int tid = threadIdx.x;
    const size_t base = (size_t)blockIdx.x * 8;
#pragma unroll
    for (int r = 0; r < 8; ++r) {
        const size_t row = base + r;
        float4 v = reinterpret_cast<const float4*>(values + row * H_)[tid];
        ushort4 o;
        o.x = (ushort_t)f2bf_u(v.x); o.y = (ushort_t)f2bf_u(v.y);
        o.z = (ushort_t)f2bf_u(v.z); o.w = (ushort_t)f2bf_u(v.w);
        *reinterpret_cast<ushort4*>(A + row * KEXT + tid * 4) = o;
    }
}

// conv(prev_att, conv_w) -> A[row][1024:1056] bf16 (loc transposed to (b,t,k))
__global__ void conv_pack(const float* __restrict__ prev, const float* __restrict__ convw,
                          ushort_t* __restrict__ A) {
    __shared__ float satt[158];       // 128 + 2*15
    __shared__ float sw[KN_ * 31];
    const int tid = threadIdx.x;
    const int b = blockIdx.y, t0 = blockIdx.x * 128;
    for (int i = tid; i < 158; i += 256) {
        int t = t0 - 15 + i;
        satt[i] = (t >= 0 && t < T_) ? prev[b * T_ + t] : 0.0f;
    }
    for (int i = tid; i < KN_ * 31; i += 256) sw[i] = convw[i];
    __syncthreads();
    for (int idx = tid; idx < 128 * KN_; idx += 256) {
        const int k = idx & 31, tl = idx >> 5;
        float acc = 0.0f;
#pragma unroll
        for (int j = 0; j < 31; ++j) acc += satt[tl + j] * sw[k * 31 + j];
        A[(size_t)(b * T_ + t0 + tl) * KEXT + H_ + k] = (ushort_t)f2bf_u(acc);
    }
}

// per u: pack [W1_w | loc_proj] row to Bm bf16 AND bias[b][u] for all 32 b
__global__ void pack_w_bias(const float* __restrict__ W1w, const float* __restrict__ locp,
                            const float* __restrict__ W2w, const float* __restrict__ q,
                            const float* __restrict__ W1b, const float* __restrict__ W2b,
                            ushort_t* __restrict__ Bm, float* __restrict__ bias) {
    const int u = blockIdx.x, tid = threadIdx.x;
    {
        float4 v = reinterpret_cast<const float4*>(W1w + (size_t)u * H_)[tid];
        ushort4 o;
        o.x = (ushort_t)f2bf_u(v.x); o.y = (ushort_t)f2bf_u(v.y);
        o.z = (ushort_t)f2bf_u(v.z); o.w = (ushort_t)f2bf_u(v.w);
        *reinterpret_cast<ushort4*>(Bm + (size_t)u * KEXT + tid * 4) = o;
    }
    if (tid < 8) {
        float4 w = reinterpret_cast<const float4*>(locp + u * KN_)[tid];
        ushort4 o2;
        o2.x = (ushort_t)f2bf_u(w.x); o2.y = (ushort_t)f2bf_u(w.y);
        o2.z = (ushort_t)f2bf_u(w.z); o2.w = (ushort_t)f2bf_u(w.w);
        *reinterpret_cast<ushort4*>(Bm + (size_t)u * KEXT + H_ + tid * 4) = o2;
    }
    const int lane = tid & 63, wave = tid >> 6;
    const float* wr = W2w + (size_t)u * H_;
    float wv[16];
#pragma unroll
    for (int i = 0; i < 16; ++i) wv[i] = wr[lane + i * 64];
    const float bb = W1b[u] + W2b[u];
#pragma unroll
    for (int j = 0; j < 8; ++j) {
        const int b = wave * 8 + j;
        const float* qr = q + b * H_;
        float acc = 0.0f;
#pragma unroll
        for (int i = 0; i < 16; ++i) acc += wv[i] * qr[lane + i * 64];
#pragma unroll
        for (int off = 32; off >= 1; off >>= 1) acc += __shfl_xor(acc, off, 64);
        if (lane == 0) bias[b * U_ + u] = acc + bb;
    }
}

// ---------- fused score GEMM: 256x256 tile, BK=32, 8 waves, 4-deep LDS pipeline ----------
// Per 32-K tile, two phases:
//  phase A: ds_read A-half0 frags (4) + all B frags (4) || stage (t+3).A -> bar
//           -> prio1 -> 16 MFMA (acc[0..3][*]) -> prio0 -> bar
//  phase B: ds_read A-half1 into same regs || stage (t+3).B -> vmcnt(8) -> bar
//           -> prio1 -> 16 MFMA (acc[4..7][*]) -> prio0 -> bar
// Counted vmcnt(8) once per tile guards tile t+1 fully landed; never 0 in main
// loop (tail: 4/0).  4 LDS buffers = prefetch distance ~4 phases (~700 cy).
// Bank swizzle: chunk c of row stored at phys = c ^ ((row>>1)&3); the >>1
// decorrelates the XOR from row parity so each quarter-wave's b128 reads hit
// all 8 bank-groups exactly 2x (2-way = free).  Applied on BOTH the staging
// global source (linear LDS dest) and the ds_read address.
__global__ __launch_bounds__(512, 2)
void score_gemm(const ushort_t* __restrict__ A, const ushort_t* __restrict__ Bm,
                const float* __restrict__ bias, const float* __restrict__ Vw,
                float* __restrict__ sacc) {
    __shared__ __align__(16) ushort_t sm[4][2][8192];   // 4 bufs x (A,B) x 256x32 bf16 = 128 KiB
    const int tid  = threadIdx.x;
    const int wave = tid >> 6;
    const int lane = tid & 63;
    const int lr   = lane & 15;
    const int quad = lane >> 4;
    const int wr64 = (wave >> 2) * 64;   // wave m-offset within each 128-half
    const int wc32 = (wave & 3) * 32;    // wave n-offset within each 128-half

    // XCD-aware swizzle: each XCD owns a contiguous band of m-tiles; n fastest
    const int hid = blockIdx.x;                     // 0..1023
    const int lin = (hid & 7) * 128 + (hid >> 3);   // bijective (1024 % 8 == 0)
    const int m0 = (lin >> 2) * 256;                // 256 m-tiles
    const int n0 = (lin & 3) * 256;                 // 4 n-tiles

    const ushort_t* Ablk = A + (size_t)m0 * KEXT;
    const ushort_t* Bblk = Bm + (size_t)n0 * KEXT;

    // staging source offsets: chunk slot s = j*512+tid -> row = s>>2, phys = s&3,
    // logical chunk c = phys ^ ((row>>1)&3)  (inverse-swizzled global source)
    int off[2];
#pragma unroll
    for (int j = 0; j < 2; ++j) {
        const int s = j * 512 + tid;
        const int row = s >> 2;
        const int c = (s & 3) ^ ((row >> 1) & 3);
        off[j] = row * KEXT + c * 8;
    }

    floatx4 acc[8][4] = {};
    short8 aF[4], bF[4];

    // prologue: stage tiles 0,1,2 into bufs 0,1,2 (order per tile: A0,A1,B0,B1)
#pragma unroll
    for (int u = 0; u < 3; ++u) {
        async_cp16(Ablk + u * 32 + off[0], &sm[u][0][wave * 512]);
        async_cp16(Ablk + u * 32 + off[1], &sm[u][0][4096 + wave * 512]);
        async_cp16(Bblk + u * 32 + off[0], &sm[u][1][wave * 512]);
        async_cp16(Bblk + u * 32 + off[1], &sm[u][1][4096 + wave * 512]);
    }
    WAITV(8);   // tile0 {A0,A1,B0,B1} landed; tiles 1,2 in flight
    BARX();

    int cur = 0, nb = 3;
#pragma unroll 1
    for (int t = 0; t < 33; ++t) {
        const ushort_t* sA = &sm[cur][0][0];
        const ushort_t* sB = &sm[cur][1][0];

        // ---- phase A: A-half0 frags + all four B frags
#pragma unroll
        for (int mi = 0; mi < 4; ++mi) {
            const int row = wr64 + mi * 16 + lr;
            aF[mi] = *reinterpret_cast<const short8*>(sA + row * 32 + (quad ^ ((row >> 1) & 3)) * 8);
        }
#pragma unroll
        for (int ni = 0; ni < 4; ++ni) {
            const int row = (ni >> 1) * 128 + wc32 + (ni & 1) * 16 + lr;
            bF[ni] = *reinterpret_cast<const short8*>(sB + row * 32 + (quad ^ ((row >> 1) & 3)) * 8);
        }
        if (t <= 29) {   // stage (t+3).A into buf nb
            const ushort_t* gA = Ablk + (t + 3) * 32;
            async_cp16(gA + off[0], &sm[nb][0][wave * 512]);
            async_cp16(gA + off[1], &sm[nb][0][4096 + wave * 512]);
        }
        BARX();          // no vmcnt needed: phase B reads only (t).A1, already guarded
        __builtin_amdgcn_s_setprio(1);
#pragma unroll
        for (int mi = 0; mi < 4; ++mi)
#pragma unroll
            for (int ni = 0; ni < 4; ++ni)
                acc[mi][ni] = __builtin_amdgcn_mfma_f32_16x16x32_bf16(aF[mi], bF[ni], acc[mi][ni], 0, 0, 0);
        __builtin_amdgcn_s_setprio(0);
        BARX();

        // ---- phase B: A-half1 frags into the same registers (bF reused)
#pragma unroll
        for (int mi = 0; mi < 4; ++mi) {
            const int row = 128 + wr64 + mi * 16 + lr;
            aF[mi] = *reinterpret_cast<const short8*>(sA + row * 32 + (quad ^ ((row >> 1) & 3)) * 8);
        }
        if (t <= 29) {   // stage (t+3).B into buf nb
            const ushort_t* gB = Bblk + (t + 3) * 32;
            async_cp16(gB + off[0], &sm[nb][1][wave * 512]);
            async_cp16(gB + off[1], &sm[nb][1][4096 + wave * 512]);
        }
        // guard tile t+1 fully landed for next phase A:
        // newer ops = (t+2).{A,B} + (t+3).{A,B} = 8 (tail: 4 / 0)
        if (t <= 29)      { WAITV(8); }
        else if (t == 30) { WAITV(4); }
        else if (t == 31) { WAITV(0); }
        BARX();
        __builtin_amdgcn_s_setprio(1);
#pragma unroll
        for (int mi = 0; mi < 4; ++mi)
#pragma unroll
            for (int ni = 0; ni < 4; ++ni)
                acc[4 + mi][ni] = __builtin_amdgcn_mfma_f32_16x16x32_bf16(aF[mi], bF[ni], acc[4 + mi][ni], 0, 0, 0);
        __builtin_amdgcn_s_setprio(0);
        BARX();

        cur = (cur + 1) & 3;
        nb  = (nb + 1) & 3;
    }

    // epilogue: sum_1 -> tanh -> *Vw -> reduce over this wave's 64 u-cols -> atomic partial
    const int bb = m0 >> 11;
    float vw[4], bv[4];
#pragma unroll
    for (int ni = 0; ni < 4; ++ni) {
        const int u = n0 + (ni >> 1) * 128 + wc32 + (ni & 1) * 16 + lr;
        vw[ni] = Vw[u];
        bv[ni] = bias[bb * U_ + u];
    }
#pragma unroll
    for (int mi = 0; mi < 8; ++mi) {
        const int mrow = m0 + (mi >> 2) * 128 + wr64 + (mi & 3) * 16 + quad * 4;
#pragma unroll
        for (int r = 0; r < 4; ++r) {
            float s = 0.0f;
#pragma unroll
            for (int ni = 0; ni < 4; ++ni)
                s += vw[ni] * fast_tanh(acc[mi][ni][r] + bv[ni]);
            s += __shfl_xor(s, 1, 64);
            s += __shfl_xor(s, 2, 64);
            s += __shfl_xor(s, 4, 64);
            s += __shfl_xor(s, 8, 64);
            if (lr == 0)
                atomicAdd(&sacc[mrow + r], s);
        }
    }
}

// ---------- softmax over T per b; writes score and attn outputs ----------
__global__ void softmax_k(const float* __restrict__ sacc, const float* __restrict__ Vb,
                          float* __restrict__ out) {
    const int b = blockIdx.x, tid = threadIdx.x;
    const int lane = tid & 63, wave = tid >> 6;
    const float vb = Vb[0];
    float v[8], e[8];
    float mx = -1e30f;
#pragma unroll
    for (int j = 0; j < 8; ++j) {
        v[j] = sacc[b * T_ + j * 256 + tid] + vb;
        out[98304 + b * T_ + j * 256 + tid] = v[j];   // score output
        mx = fmaxf(mx, v[j]);
    }
#pragma unroll
    for (int off = 32; off >= 1; off >>= 1) mx = fmaxf(mx, __shfl_xor(mx, off, 64));
    __shared__ float sm[4], ss[4];
    if (lane == 0) sm[wave] = mx;
    __syncthreads();
    mx = fmaxf(fmaxf(sm[0], sm[1]), fmaxf(sm[2], sm[3]));
    float sum = 0.0f;
#pragma unroll
    for (int j = 0; j < 8; ++j) { e[j] = __expf(v[j] - mx); sum += e[j]; }
#pragma unroll
    for (int off = 32; off >= 1; off >>= 1) sum += __shfl_xor(sum, off, 64);
    if (lane == 0) ss[wave] = sum;
    __syncthreads();
    sum = ss[0] + ss[1] + ss[2] + ss[3];
    const float inv = 1.0f / sum;
#pragma unroll
    for (int j = 0; j < 8; ++j)
        out[32768 + b * T_ + j * 256 + tid] = e[j] * inv;  // attention output
}

// ---------- context = sum_t attn[b,t] * values[b,t,h] (bf16 copy) ----------
__global__ void context_k(const ushort_t* __restrict__ A, const float* __restrict__ attn,
                          float* __restrict__ ctx) {
    const int b = blockIdx.y, tc = blockIdx.x, tid = threadIdx.x;
    __shared__ float sa[128];
    if (tid < 128) sa[tid] = attn[b * T_ + tc * 128 + tid];
    __syncthreads();
    const int hh = (tid & 127) * 8;   // 8 h-elements per thread
    const int tp = tid >> 7;          // row-pair 0/1
    const ushort_t* base = A + (size_t)(b * T_ + tc * 128 + tp) * KEXT + hh;
    float a[8] = {0, 0, 0, 0, 0, 0, 0, 0};
    for (int t = 0; t < 128; t += 2) {
        const float w = sa[t + tp];
        uint4 u = *reinterpret_cast<const uint4*>(base + (size_t)t * KEXT);
        a[0] += w * bflo(u.x); a[1] += w * bfhi(u.x);
        a[2] += w * bflo(u.y); a[3] += w * bfhi(u.y);
        a[4] += w * bflo(u.z); a[5] += w * bfhi(u.z);
        a[6] += w * bflo(u.w); a[7] += w * bfhi(u.w);
    }
#pragma unroll
    for (int j = 0; j < 8; ++j)
        atomicAdd(&ctx[b * H_ + hh + j], a[j]);
}

// ---------- launch ----------
extern "C" void kernel_launch(void* const* d_in, const int* in_sizes, int n_in,
                              void* d_out, int out_size, void* d_ws, size_t ws_size,
                              hipStream_t stream) {
    const float* query    = (const float*)d_in[0];
    const float* values   = (const float*)d_in[1];
    const float* prev_att = (const float*)d_in[2];
    const float* W1w      = (const float*)d_in[3];
    const float* W1b      = (const float*)d_in[4];
    const float* W2w      = (const float*)d_in[5];
    const float* W2b      = (const float*)d_in[6];
    const float* Vw       = (const float*)d_in[7];
    const float* Vb       = (const float*)d_in[8];
    const float* convw    = (const float*)d_in[9];
    const float* locp     = (const float*)d_in[10];
    float* out = (float*)d_out;

    char* ws = (char*)d_ws;
    ushort_t* A    = (ushort_t*)(ws);
    ushort_t* Bm   = (ushort_t*)(ws + 138412032);
    float*    bias = (float*)(ws + 140574720);
    float*    sacc = (float*)(ws + 140705792);

    hipMemsetAsync(sacc, 0, BT_ * sizeof(float), stream);
    hipMemsetAsync(out, 0, 32768 * sizeof(float), stream);   // context via atomics

    pack_values<<<BT_ / 8, 256, 0, stream>>>(values, A);
    conv_pack<<<dim3(16, 32), 256, 0, stream>>>(prev_att, convw, A);
    pack_w_bias<<<1024, 256, 0, stream>>>(W1w, locp, W2w, query, W1b, W2b, Bm, bias);
    score_gemm<<<1024, 512, 0, stream>>>(A, Bm, bias, Vw, sacc);
    softmax_k<<<32, 256, 0, stream>>>(sacc, Vb, out);
    context_k<<<dim3(16, 32), 256, 0, stream>>>(A, out + 32768, out);
}